// Round 2
// baseline (659.526 us; speedup 1.0000x reference)
//
#include <hip/hip_runtime.h>

typedef unsigned short u16;
typedef __attribute__((ext_vector_type(8))) __bf16 bf16x8;
typedef __attribute__((ext_vector_type(8))) short short8;
typedef __attribute__((ext_vector_type(4))) float f32x4;

#define NE 8            // experts

#define SBAR()      asm volatile("s_barrier" ::: "memory")
#define WAIT_LGKM0() do { asm volatile("s_waitcnt lgkmcnt(0)" ::: "memory"); \
                          __builtin_amdgcn_sched_barrier(0); } while (0)
#define WAIT_VM4()  asm volatile("s_waitcnt vmcnt(4)" ::: "memory")
#define WAIT_VM0()  asm volatile("s_waitcnt vmcnt(0)" ::: "memory")

__device__ __forceinline__ u16 f2bf(float f) {
    union { float f; unsigned u; } v; v.f = f;
    unsigned u = v.u;
    return (u16)((u + 0x7fffu + ((u >> 16) & 1u)) >> 16);
}

__device__ __forceinline__ f32x4 mfma16(short8 a, short8 b, f32x4 c) {
    return __builtin_amdgcn_mfma_f32_16x16x32_bf16(
        __builtin_bit_cast(bf16x8, a), __builtin_bit_cast(bf16x8, b), c, 0, 0, 0);
}

// async global->LDS, 16B per lane; lds dest = wave-uniform base + lane*16
__device__ __forceinline__ void gl2lds(const u16* g, u16* l) {
    __builtin_amdgcn_global_load_lds((const __attribute__((address_space(1))) void*)g,
                                     (__attribute__((address_space(3))) void*)l,
                                     16, 0, 0);
}

// ---------------- w2 fp32 -> bf16 (grid-stride, float4) ----------------
__global__ void cvt_kernel(const float* __restrict__ in, u16* __restrict__ out, size_t n4) {
    size_t i = (size_t)blockIdx.x * blockDim.x + threadIdx.x;
    size_t stride = (size_t)gridDim.x * blockDim.x;
    for (; i < n4; i += stride) {
        float4 v = ((const float4*)in)[i];
        ushort4 o;
        o.x = f2bf(v.x); o.y = f2bf(v.y); o.z = f2bf(v.z); o.w = f2bf(v.w);
        ((ushort4*)out)[i] = o;
    }
}

// ---- w1/w3 -> bf16 wc[e][2H][D], 16-row interleave:
//      H-col j -> w1 at wc row (j>>4)*32 + (j&15); w3 at +16.
__global__ void cvt_w13_kernel(const float* __restrict__ w1, const float* __restrict__ w3,
                               u16* __restrict__ wc, int H, int D) {
    size_t n = (size_t)NE * H * (D / 4);
    size_t i = (size_t)blockIdx.x * blockDim.x + threadIdx.x;
    size_t stride = (size_t)gridDim.x * blockDim.x;
    int d4n = D / 4;
    for (; i < n; i += stride) {
        int d4 = (int)(i % d4n);
        size_t rem = i / d4n;
        int j = (int)(rem % H);
        int e = (int)(rem / H);
        float4 v1 = ((const float4*)w1)[i];
        float4 v3 = ((const float4*)w3)[i];
        ushort4 o1, o3;
        o1.x = f2bf(v1.x); o1.y = f2bf(v1.y); o1.z = f2bf(v1.z); o1.w = f2bf(v1.w);
        o3.x = f2bf(v3.x); o3.y = f2bf(v3.y); o3.z = f2bf(v3.z); o3.w = f2bf(v3.w);
        int wcrow = ((j >> 4) << 5) + (j & 15);
        size_t o = (((size_t)e * 2 * H + wcrow) * d4n + d4);
        ((ushort4*)wc)[o] = o1;
        ((ushort4*)wc)[o + (size_t)16 * d4n] = o3;
    }
}

// ---------------- router: noisy top-2 gating + x->bf16, one wave per token ----------------
__global__ void router_kernel(const float* __restrict__ x, const float* __restrict__ noise,
                              const float* __restrict__ rw, const float* __restrict__ rb,
                              const float* __restrict__ nw, const float* __restrict__ nb,
                              int* __restrict__ tops, float* __restrict__ gpair,
                              u16* __restrict__ xb, int T, int D) {
    int wv = threadIdx.x >> 6;
    int lane = threadIdx.x & 63;
    int t = blockIdx.x * 4 + wv;
    if (t >= T) return;

    const float4* x4 = (const float4*)(x + (size_t)t * D) + lane * 4;
    float4 xv0 = x4[0], xv1 = x4[1], xv2 = x4[2], xv3 = x4[3];

    {
        ushort4 s0, s1, s2, s3;
        s0.x = f2bf(xv0.x); s0.y = f2bf(xv0.y); s0.z = f2bf(xv0.z); s0.w = f2bf(xv0.w);
        s1.x = f2bf(xv1.x); s1.y = f2bf(xv1.y); s1.z = f2bf(xv1.z); s1.w = f2bf(xv1.w);
        s2.x = f2bf(xv2.x); s2.y = f2bf(xv2.y); s2.z = f2bf(xv2.z); s2.w = f2bf(xv2.w);
        s3.x = f2bf(xv3.x); s3.y = f2bf(xv3.y); s3.z = f2bf(xv3.z); s3.w = f2bf(xv3.w);
        ushort4* o = (ushort4*)(xb + (size_t)t * D + lane * 16);
        o[0] = s0; o[1] = s1; o[2] = s2; o[3] = s3;
    }

    float acc[2 * NE];
#pragma unroll
    for (int e = 0; e < NE; e++) {
        const float4* w4 = (const float4*)(rw + (size_t)e * D) + lane * 4;
        float4 a = w4[0], b = w4[1], c = w4[2], d = w4[3];
        acc[e] = xv0.x*a.x + xv0.y*a.y + xv0.z*a.z + xv0.w*a.w
               + xv1.x*b.x + xv1.y*b.y + xv1.z*b.z + xv1.w*b.w
               + xv2.x*c.x + xv2.y*c.y + xv2.z*c.z + xv2.w*c.w
               + xv3.x*d.x + xv3.y*d.y + xv3.z*d.z + xv3.w*d.w;
        const float4* v4 = (const float4*)(nw + (size_t)e * D) + lane * 4;
        a = v4[0]; b = v4[1]; c = v4[2]; d = v4[3];
        acc[NE + e] = xv0.x*a.x + xv0.y*a.y + xv0.z*a.z + xv0.w*a.w
                    + xv1.x*b.x + xv1.y*b.y + xv1.z*b.z + xv1.w*b.w
                    + xv2.x*c.x + xv2.y*c.y + xv2.z*c.z + xv2.w*c.w
                    + xv3.x*d.x + xv3.y*d.y + xv3.z*d.z + xv3.w*d.w;
    }
#pragma unroll
    for (int m = 1; m < 64; m <<= 1) {
#pragma unroll
        for (int k = 0; k < 2 * NE; k++) acc[k] += __shfl_xor(acc[k], m);
    }

    if (lane == 0) {
        float v0 = -1e30f, v1 = -1e30f;
        int i0 = 0, i1 = 0;
#pragma unroll
        for (int e = 0; e < NE; e++) {
            float z = acc[NE + e] + nb[e];
            float sp = (z > 20.f) ? z : log1pf(expf(z));
            float nv = acc[e] + rb[e] + noise[(size_t)t * NE + e] * sp;
            if (nv > v0) { v1 = v0; i1 = i0; v0 = nv; i0 = e; }
            else if (nv > v1) { v1 = nv; i1 = e; }
        }
        float e1 = expf(v1 - v0);
        float inv = 1.f / (1.f + e1);
        tops[t] = i0 | (i1 << 8);
        gpair[2 * t]     = inv;
        gpair[2 * t + 1] = e1 * inv;
    }
}

// ---------------- build: deterministic per-expert compaction (no atomics) ----------------
__global__ void build_kernel(const int* __restrict__ tops, const float* __restrict__ gpair,
                             int* __restrict__ counts, int* __restrict__ list,
                             float* __restrict__ glist, int* __restrict__ tokslot, int T) {
    int e = blockIdx.x;
    int tid = threadIdx.x, lane = tid & 63, wv = tid >> 6;
    __shared__ int wsum[4];
    __shared__ int sbase;
    if (tid == 0) sbase = 0;
    __syncthreads();
    for (int t0 = 0; t0 < T; t0 += 256) {
        int t = t0 + tid;
        int pk = tops[t];
        int i0 = pk & 0xff, i1 = (pk >> 8) & 0xff;
        bool f0 = (i0 == e), f1 = (i1 == e);
        bool f = f0 || f1;
        unsigned long long m = __ballot(f);
        int lpos = __popcll(m & (((unsigned long long)1 << lane) - 1ull));
        if (lane == 0) wsum[wv] = __popcll(m);
        __syncthreads();
        int woff = sbase;
        for (int w = 0; w < wv; w++) woff += wsum[w];
        int tot = wsum[0] + wsum[1] + wsum[2] + wsum[3];
        if (f) {
            int pos = woff + lpos;
            list[e * T + pos]  = t;
            glist[e * T + pos] = f0 ? gpair[2 * t] : gpair[2 * t + 1];
            tokslot[2 * t + (f0 ? 0 : 1)] = (e << 16) | pos;
        }
        __syncthreads();
        if (tid == 0) sbase += tot;
    }
    __syncthreads();
    if (tid == 0) counts[e] = sbase;
}

// ---------------- scan + compact block map (256-row M-blocks): bmap[b]=(e<<16)|mblk ----------------
__global__ void scan_kernel(const int* __restrict__ counts, int* __restrict__ offsets,
                            int* __restrict__ bmap, int* __restrict__ nb) {
    if (threadIdx.x == 0 && blockIdx.x == 0) {
        int s = 0, t = 0;
        for (int e = 0; e < NE; e++) {
            offsets[e] = s;
            int c = counts[e];
            s += c;
            int m = (c + 255) >> 8;
            for (int i = 0; i < m; i++) bmap[t++] = (e << 16) | i;
        }
        offsets[NE] = s;
        nb[0] = t;
    }
}

// ===================== 256x256 phase-split GEMM (BK=32, triple-buffer, counted vmcnt) ===========
// 512 threads = 8 waves (2M x 4N). Per-wave C: 128x64 = acc[8][4] 16x16 frags.
// LDS: 3 K-tile buffers x (A 16KB + B 16KB) = 96KB. Stage tile t+2 during tile t.
// Swizzle: LDS slot (row, qs) holds global chunk qs ^ ((row>>1)&3); reads use same XOR -> 2-way banks.

#define FRAG_READS(abase, bbase, af, bf, mibase) do { \
        _Pragma("unroll") \
        for (int mi = 0; mi < 4; mi++) \
            af[mi] = *(const short8*)((abase) + aoff + ((mibase) + mi) * 512); \
        if (bf##_load) { \
            _Pragma("unroll") \
            for (int ni = 0; ni < 4; ni++) \
                bf[ni] = *(const short8*)((bbase) + boff + ni * 512); \
        } } while (0)

#define MFMA16X(af, bf, mibase) do { \
        __builtin_amdgcn_s_setprio(1); \
        _Pragma("unroll") \
        for (int mi = 0; mi < 4; mi++) \
            _Pragma("unroll") \
            for (int ni = 0; ni < 4; ni++) \
                acc[(mibase) + mi][ni] = mfma16(af[mi], bf[ni], acc[(mibase) + mi][ni]); \
        __builtin_amdgcn_s_setprio(0); } while (0)

// ---------------- GEMM1: xb(gathered) @ wc^T; epilogue silu(h1)*h3*gate -> hb ----------------
__launch_bounds__(512, 2)
__global__ void gemm1_kernel(const u16* __restrict__ xb, const u16* __restrict__ wc,
                             const int* __restrict__ counts, const int* __restrict__ offsets,
                             const int* __restrict__ list, const float* __restrict__ glist,
                             const int* __restrict__ bmap, const int* __restrict__ nb,
                             u16* __restrict__ hb, int T, int D, int H) {
    if ((int)blockIdx.y >= nb[0]) return;
    int info = bmap[blockIdx.y];
    int e = info >> 16, mblk = info & 0xffff, nblk = blockIdx.x;
    int count = counts[e];

    __shared__ u16 sA[3 * 8192];
    __shared__ u16 sB[3 * 8192];
    __shared__ int stok[256];
    __shared__ float sgate[256];

    int tid = threadIdx.x;
    int lane = tid & 63, wid = tid >> 6;

    if (tid < 256) {
        int rr = min(mblk * 256 + tid, count - 1);
        stok[tid]  = list[e * T + rr];
        sgate[tid] = glist[e * T + rr];
    }
    __syncthreads();

    const u16* wcp = wc + ((size_t)e * 2 * H + nblk * 256) * D;

    // staging: thread -> (srow 0..127, qs 0..3); global chunk pre-swizzled
    int srow = tid >> 2, qs = tid & 3;
    int cchk = qs ^ ((srow >> 1) & 3);
    const u16* pa0 = xb + (size_t)stok[srow] * D + cchk * 8;
    const u16* pa1 = xb + (size_t)stok[128 + srow] * D + cchk * 8;
    const u16* pb0 = wcp + (size_t)srow * D + cchk * 8;
    const u16* pb1 = wcp + (size_t)(128 + srow) * D + cchk * 8;
    u16* dstA = sA + wid * 512;     // + buf*8192 (+4096 for half1)
    u16* dstB = sB + wid * 512;

    // frag-read offsets (swizzled chunk is per-lane constant)
    int r = lane & 15, q = lane >> 4;
    int cq = q ^ ((r >> 1) & 3);
    int wr = wid >> 2, wc4 = wid & 3;
    int aoff = (wr * 128 + r) * 32 + cq * 8;
    int boff = (wc4 * 64 + r) * 32 + cq * 8;

    f32x4 acc[8][4];
#pragma unroll
    for (int mi = 0; mi < 8; mi++)
#pragma unroll
        for (int ni = 0; ni < 4; ni++) acc[mi][ni] = (f32x4)0.f;

    // prologue: stage tiles 0,1
    gl2lds(pa0, dstA);          gl2lds(pb0, dstB);
    gl2lds(pa1, dstA + 4096);   gl2lds(pb1, dstB + 4096);
    pa0 += 32; pa1 += 32; pb0 += 32; pb1 += 32;
    gl2lds(pa0, dstA + 8192);          gl2lds(pb0, dstB + 8192);
    gl2lds(pa1, dstA + 8192 + 4096);   gl2lds(pb1, dstB + 8192 + 4096);
    pa0 += 32; pa1 += 32; pb0 += 32; pb1 += 32;
    WAIT_VM4();
    SBAR();

    const int nt = D >> 5;      // 32 K-tiles
    int cur = 0;
    for (int t = 0; t < nt; ++t) {
        const u16* abase = sA + cur * 8192;
        const u16* bbase = sB + cur * 8192;
        int stg = cur + 2; if (stg >= 3) stg -= 3;
        u16* asg = sA + stg * 8192 + wid * 512;
        u16* bsg = sB + stg * 8192 + wid * 512;
        bool st = (t + 2 < nt);

        short8 af[4], bf[4];
        const bool bf_load = true;
        // ---- phase 0: frags mi 0..3 + all B; stage half 0 of tile t+2
        FRAG_READS(abase, bbase, af, bf, 0);
        if (st) { gl2lds(pa0, asg); gl2lds(pb0, bsg); }
        SBAR();
        WAIT_LGKM0();
        MFMA16X(af, bf, 0);
        SBAR();
        // ---- phase 1: frags mi 4..7 (reuse B); stage half 1 of tile t+2
#pragma unroll
        for (int mi = 0; mi < 4; mi++)
            af[mi] = *(const short8*)(abase + aoff + (4 + mi) * 512);
        if (st) {
            gl2lds(pa1, asg + 4096); gl2lds(pb1, bsg + 4096);
            pa0 += 32; pa1 += 32; pb0 += 32; pb1 += 32;
        }
        SBAR();
        WAIT_LGKM0();
        MFMA16X(af, bf, 4);
        if (st) { WAIT_VM4(); } else { WAIT_VM0(); }
        SBAR();
        cur++; if (cur >= 3) cur = 0;
    }

    // epilogue: acc[mi][2p]=h1, acc[mi][2p+1]=h3 of same H-cols (16-row interleaved wc)
    int hrow0 = offsets[e];
#pragma unroll
    for (int mi = 0; mi < 8; mi++) {
#pragma unroll
        for (int p = 0; p < 2; p++) {
            int col = nblk * 128 + wc4 * 32 + p * 16 + r;
#pragma unroll
            for (int tt = 0; tt < 4; tt++) {
                int lrow = wr * 128 + mi * 16 + q * 4 + tt;
                int grow = mblk * 256 + lrow;
                if (grow < count) {
                    float v = acc[mi][2 * p][tt];
                    float hv = v / (1.f + expf(-v)) * acc[mi][2 * p + 1][tt] * sgate[lrow];
                    hb[(size_t)(hrow0 + grow) * H + col] = f2bf(hv);
                }
            }
        }
    }
}

// ---------------- GEMM2: o2[row] = h[row] @ w2^T ----------------
__launch_bounds__(512, 2)
__global__ void gemm2_kernel(const u16* __restrict__ hb, const u16* __restrict__ w2b,
                             const int* __restrict__ counts, const int* __restrict__ offsets,
                             const int* __restrict__ bmap, const int* __restrict__ nb,
                             float* __restrict__ o2, int T, int D, int H) {
    if ((int)blockIdx.y >= nb[0]) return;
    int info = bmap[blockIdx.y];
    int e = info >> 16, mblk = info & 0xffff, nblk = blockIdx.x;
    int count = counts[e];

    __shared__ u16 sA[3 * 8192];
    __shared__ u16 sB[3 * 8192];

    int tid = threadIdx.x;
    int lane = tid & 63, wid = tid >> 6;
    int off0 = offsets[e];
    const u16* w2p = w2b + ((size_t)e * D + nblk * 256) * H;

    int srow = tid >> 2, qs = tid & 3;
    int cchk = qs ^ ((srow >> 1) & 3);
    int ra0 = min(mblk * 256 + srow, count - 1);
    int ra1 = min(mblk * 256 + 128 + srow, count - 1);
    const u16* pa0 = hb + (size_t)(off0 + ra0) * H + cchk * 8;
    const u16* pa1 = hb + (size_t)(off0 + ra1) * H + cchk * 8;
    const u16* pb0 = w2p + (size_t)srow * H + cchk * 8;
    const u16* pb1 = w2p + (size_t)(128 + srow) * H + cchk * 8;
    u16* dstA = sA + wid * 512;
    u16* dstB = sB + wid * 512;

    int r = lane & 15, q = lane >> 4;
    int cq = q ^ ((r >> 1) & 3);
    int wr = wid >> 2, wc4 = wid & 3;
    int aoff = (wr * 128 + r) * 32 + cq * 8;
    int boff = (wc4 * 64 + r) * 32 + cq * 8;

    f32x4 acc[8][4];
#pragma unroll
    for (int mi = 0; mi < 8; mi++)
#pragma unroll
        for (int ni = 0; ni < 4; ni++) acc[mi][ni] = (f32x4)0.f;

    gl2lds(pa0, dstA);          gl2lds(pb0, dstB);
    gl2lds(pa1, dstA + 4096);   gl2lds(pb1, dstB + 4096);
    pa0 += 32; pa1 += 32; pb0 += 32; pb1 += 32;
    gl2lds(pa0, dstA + 8192);          gl2lds(pb0, dstB + 8192);
    gl2lds(pa1, dstA + 8192 + 4096);   gl2lds(pb1, dstB + 8192 + 4096);
    pa0 += 32; pa1 += 32; pb0 += 32; pb1 += 32;
    WAIT_VM4();
    SBAR();

    const int nt = H >> 5;      // 64 K-tiles
    int cur = 0;
    for (int t = 0; t < nt; ++t) {
        const u16* abase = sA + cur * 8192;
        const u16* bbase = sB + cur * 8192;
        int stg = cur + 2; if (stg >= 3) stg -= 3;
        u16* asg = sA + stg * 8192 + wid * 512;
        u16* bsg = sB + stg * 8192 + wid * 512;
        bool st = (t + 2 < nt);

        short8 af[4], bf[4];
        const bool bf_load = true;
        FRAG_READS(abase, bbase, af, bf, 0);
        if (st) { gl2lds(pa0, asg); gl2lds(pb0, bsg); }
        SBAR();
        WAIT_LGKM0();
        MFMA16X(af, bf, 0);
        SBAR();
#pragma unroll
        for (int mi = 0; mi < 4; mi++)
            af[mi] = *(const short8*)(abase + aoff + (4 + mi) * 512);
        if (st) {
            gl2lds(pa1, asg + 4096); gl2lds(pb1, bsg + 4096);
            pa0 += 32; pa1 += 32; pb0 += 32; pb1 += 32;
        }
        SBAR();
        WAIT_LGKM0();
        MFMA16X(af, bf, 4);
        if (st) { WAIT_VM4(); } else { WAIT_VM0(); }
        SBAR();
        cur++; if (cur >= 3) cur = 0;
    }

    // epilogue: coalesced packed fp32 stores
#pragma unroll
    for (int mi = 0; mi < 8; mi++) {
#pragma unroll
        for (int tt = 0; tt < 4; tt++) {
            int grow = mblk * 256 + wr * 128 + mi * 16 + q * 4 + tt;
            if (grow < count) {
#pragma unroll
                for (int ni = 0; ni < 4; ni++) {
                    int col = nblk * 256 + wc4 * 64 + ni * 16 + r;
                    o2[(size_t)(off0 + grow) * D + col] = acc[mi][ni][tt];
                }
            }
        }
    }
}

// ---------------- combine: out[t] = o2[row0(t)] + o2[row1(t)] ----------------
__global__ void combine_kernel(const float* __restrict__ o2, const int* __restrict__ tokslot,
                               const int* __restrict__ offsets, float* __restrict__ out, int D) {
    int t = blockIdx.x;
    int s0 = tokslot[2 * t], s1 = tokslot[2 * t + 1];
    size_t r0 = offsets[s0 >> 16] + (s0 & 0xffff);
    size_t r1 = offsets[s1 >> 16] + (s1 & 0xffff);
    int c = threadIdx.x * 4;
    float4 a = *(const float4*)(o2 + r0 * D + c);
    float4 b = *(const float4*)(o2 + r1 * D + c);
    float4 o; o.x = a.x + b.x; o.y = a.y + b.y; o.z = a.z + b.z; o.w = a.w + b.w;
    *(float4*)(out + (size_t)t * D + c) = o;
}

extern "C" void kernel_launch(void* const* d_in, const int* in_sizes, int n_in,
                              void* d_out, int out_size, void* d_ws, size_t ws_size,
                              hipStream_t stream) {
    const float* x     = (const float*)d_in[0];
    const float* noise = (const float*)d_in[1];
    const float* rw    = (const float*)d_in[2];
    const float* rb    = (const float*)d_in[3];
    const float* nw    = (const float*)d_in[4];
    const float* nb_   = (const float*)d_in[5];
    const float* w1    = (const float*)d_in[6];
    const float* w2    = (const float*)d_in[7];
    const float* w3    = (const float*)d_in[8];
    float* out = (float*)d_out;

    const int E = NE;
    const int D = in_sizes[2] / E;              // 1024
    const int T = in_sizes[0] / D;              // 8192
    const int H = in_sizes[6] / (E * D);        // 2048

    auto al = [](size_t v) { return (v + 255) & ~(size_t)255; };
    char* p = (char*)d_ws;
    size_t o_counts  = 0;                                     // 8 ints
    size_t o_offsets = 64;                                    // 9 ints
    size_t o_nb      = 128;                                   // 1 int
    size_t o_bmap    = 256;                                   // up to 2T/256+NE ints
    size_t o_tslot   = al(o_bmap  + 2048);
    size_t o_list    = al(o_tslot + (size_t)2 * T * 4);
    size_t o_glist   = al(o_list  + (size_t)E * T * 4);
    size_t o_xb      = al(o_glist + (size_t)E * T * 4);
    size_t o_wc      = al(o_xb    + (size_t)T * D * 2);       // wc reused as o2 after gemm1
    size_t o_w2b     = al(o_wc    + (size_t)E * 2 * H * D * 2);
    size_t o_hb      = al(o_w2b   + (size_t)E * D * H * 2);

    int*   counts  = (int*)(p + o_counts);
    int*   offsets = (int*)(p + o_offsets);
    int*   nblk    = (int*)(p + o_nb);
    int*   bmap    = (int*)(p + o_bmap);
    int*   tokslot = (int*)(p + o_tslot);
    int*   list    = (int*)(p + o_list);
    float* glist   = (float*)(p + o_glist);
    u16*   xb      = (u16*)(p + o_xb);
    u16*   wc      = (u16*)(p + o_wc);
    float* o2      = (float*)(p + o_wc);        // overlay: wc dead after gemm1
    u16*   w2b     = (u16*)(p + o_w2b);
    u16*   hb      = (u16*)(p + o_hb);
    // tops/gpair overlay head of hb region: dead before gemm1 writes hb.
    int*   tops    = (int*)(p + o_hb);                        // T ints   (32 KB)
    float* gpair   = (float*)(p + o_hb + (size_t)T * 4);      // 2T floats (64 KB)

    cvt_w13_kernel<<<2048, 256, 0, stream>>>(w1, w3, wc, H, D);
    cvt_kernel<<<2048, 256, 0, stream>>>(w2, w2b, (size_t)E * D * H / 4);

    router_kernel<<<(T + 3) / 4, 256, 0, stream>>>(x, noise, rw, rb, nw, nb_,
                                                   tops, gpair, xb, T, D);
    build_kernel<<<NE, 256, 0, stream>>>(tops, gpair, counts, list, glist, tokslot, T);
    scan_kernel<<<1, 64, 0, stream>>>(counts, offsets, bmap, nblk);

    int maxb = 2 * T / 256 + NE;                // 72
    dim3 g1(2 * H / 256, maxb, 1);              // (16, 72)
    gemm1_kernel<<<g1, 512, 0, stream>>>(xb, wc, counts, offsets, list, glist,
                                         bmap, nblk, hb, T, D, H);
    dim3 g2(D / 256, maxb, 1);                  // (4, 72)
    gemm2_kernel<<<g2, 512, 0, stream>>>(hb, w2b, counts, offsets,
                                         bmap, nblk, o2, T, D, H);
    combine_kernel<<<T, 256, 0, stream>>>(o2, tokslot, offsets, out, D);
}

// Round 3
// 625.095 us; speedup vs baseline: 1.0551x; 1.0551x over previous
//
#include <hip/hip_runtime.h>

typedef unsigned short u16;
typedef __attribute__((ext_vector_type(8))) __bf16 bf16x8;
typedef __attribute__((ext_vector_type(8))) short short8;
typedef __attribute__((ext_vector_type(4))) float f32x4;

#define NE 8            // experts

#define SBAR()      asm volatile("s_barrier" ::: "memory")
#define WAIT_LGKM0() do { asm volatile("s_waitcnt lgkmcnt(0)" ::: "memory"); \
                          __builtin_amdgcn_sched_barrier(0); } while (0)
#define WAIT_VM6()  asm volatile("s_waitcnt vmcnt(6)" ::: "memory")
#define WAIT_VM8()  asm volatile("s_waitcnt vmcnt(8)" ::: "memory")

__device__ __forceinline__ u16 f2bf(float f) {
    union { float f; unsigned u; } v; v.f = f;
    unsigned u = v.u;
    return (u16)((u + 0x7fffu + ((u >> 16) & 1u)) >> 16);
}

__device__ __forceinline__ f32x4 mfma16(short8 a, short8 b, f32x4 c) {
    return __builtin_amdgcn_mfma_f32_16x16x32_bf16(
        __builtin_bit_cast(bf16x8, a), __builtin_bit_cast(bf16x8, b), c, 0, 0, 0);
}

// async global->LDS, 16B per lane; lds dest = wave-uniform base + lane*16
__device__ __forceinline__ void gl2lds(const u16* g, u16* l) {
    __builtin_amdgcn_global_load_lds((const __attribute__((address_space(1))) void*)g,
                                     (__attribute__((address_space(3))) void*)l,
                                     16, 0, 0);
}

// ---------------- w2 fp32 -> bf16 (grid-stride, float4) ----------------
__global__ void cvt_kernel(const float* __restrict__ in, u16* __restrict__ out, size_t n4) {
    size_t i = (size_t)blockIdx.x * blockDim.x + threadIdx.x;
    size_t stride = (size_t)gridDim.x * blockDim.x;
    for (; i < n4; i += stride) {
        float4 v = ((const float4*)in)[i];
        ushort4 o;
        o.x = f2bf(v.x); o.y = f2bf(v.y); o.z = f2bf(v.z); o.w = f2bf(v.w);
        ((ushort4*)out)[i] = o;
    }
}

// ---- w1/w3 -> bf16 wc[e][2H][D], 16-row interleave:
//      H-col j -> w1 at wc row (j>>4)*32 + (j&15); w3 at +16.
__global__ void cvt_w13_kernel(const float* __restrict__ w1, const float* __restrict__ w3,
                               u16* __restrict__ wc, int H, int D) {
    size_t n = (size_t)NE * H * (D / 4);
    size_t i = (size_t)blockIdx.x * blockDim.x + threadIdx.x;
    size_t stride = (size_t)gridDim.x * blockDim.x;
    int d4n = D / 4;
    for (; i < n; i += stride) {
        int d4 = (int)(i % d4n);
        size_t rem = i / d4n;
        int j = (int)(rem % H);
        int e = (int)(rem / H);
        float4 v1 = ((const float4*)w1)[i];
        float4 v3 = ((const float4*)w3)[i];
        ushort4 o1, o3;
        o1.x = f2bf(v1.x); o1.y = f2bf(v1.y); o1.z = f2bf(v1.z); o1.w = f2bf(v1.w);
        o3.x = f2bf(v3.x); o3.y = f2bf(v3.y); o3.z = f2bf(v3.z); o3.w = f2bf(v3.w);
        int wcrow = ((j >> 4) << 5) + (j & 15);
        size_t o = (((size_t)e * 2 * H + wcrow) * d4n + d4);
        ((ushort4*)wc)[o] = o1;
        ((ushort4*)wc)[o + (size_t)16 * d4n] = o3;
    }
}

// ---------------- router: noisy top-2 gating + x->bf16, one wave per token ----------------
__global__ void router_kernel(const float* __restrict__ x, const float* __restrict__ noise,
                              const float* __restrict__ rw, const float* __restrict__ rb,
                              const float* __restrict__ nw, const float* __restrict__ nb,
                              int* __restrict__ tops, float* __restrict__ gpair,
                              u16* __restrict__ xb, int T, int D) {
    int wv = threadIdx.x >> 6;
    int lane = threadIdx.x & 63;
    int t = blockIdx.x * 4 + wv;
    if (t >= T) return;

    const float4* x4 = (const float4*)(x + (size_t)t * D) + lane * 4;
    float4 xv0 = x4[0], xv1 = x4[1], xv2 = x4[2], xv3 = x4[3];

    {
        ushort4 s0, s1, s2, s3;
        s0.x = f2bf(xv0.x); s0.y = f2bf(xv0.y); s0.z = f2bf(xv0.z); s0.w = f2bf(xv0.w);
        s1.x = f2bf(xv1.x); s1.y = f2bf(xv1.y); s1.z = f2bf(xv1.z); s1.w = f2bf(xv1.w);
        s2.x = f2bf(xv2.x); s2.y = f2bf(xv2.y); s2.z = f2bf(xv2.z); s2.w = f2bf(xv2.w);
        s3.x = f2bf(xv3.x); s3.y = f2bf(xv3.y); s3.z = f2bf(xv3.z); s3.w = f2bf(xv3.w);
        ushort4* o = (ushort4*)(xb + (size_t)t * D + lane * 16);
        o[0] = s0; o[1] = s1; o[2] = s2; o[3] = s3;
    }

    float acc[2 * NE];
#pragma unroll
    for (int e = 0; e < NE; e++) {
        const float4* w4 = (const float4*)(rw + (size_t)e * D) + lane * 4;
        float4 a = w4[0], b = w4[1], c = w4[2], d = w4[3];
        acc[e] = xv0.x*a.x + xv0.y*a.y + xv0.z*a.z + xv0.w*a.w
               + xv1.x*b.x + xv1.y*b.y + xv1.z*b.z + xv1.w*b.w
               + xv2.x*c.x + xv2.y*c.y + xv2.z*c.z + xv2.w*c.w
               + xv3.x*d.x + xv3.y*d.y + xv3.z*d.z + xv3.w*d.w;
        const float4* v4 = (const float4*)(nw + (size_t)e * D) + lane * 4;
        a = v4[0]; b = v4[1]; c = v4[2]; d = v4[3];
        acc[NE + e] = xv0.x*a.x + xv0.y*a.y + xv0.z*a.z + xv0.w*a.w
                    + xv1.x*b.x + xv1.y*b.y + xv1.z*b.z + xv1.w*b.w
                    + xv2.x*c.x + xv2.y*c.y + xv2.z*c.z + xv2.w*c.w
                    + xv3.x*d.x + xv3.y*d.y + xv3.z*d.z + xv3.w*d.w;
    }
#pragma unroll
    for (int m = 1; m < 64; m <<= 1) {
#pragma unroll
        for (int k = 0; k < 2 * NE; k++) acc[k] += __shfl_xor(acc[k], m);
    }

    if (lane == 0) {
        float v0 = -1e30f, v1 = -1e30f;
        int i0 = 0, i1 = 0;
#pragma unroll
        for (int e = 0; e < NE; e++) {
            float z = acc[NE + e] + nb[e];
            float sp = (z > 20.f) ? z : log1pf(expf(z));
            float nv = acc[e] + rb[e] + noise[(size_t)t * NE + e] * sp;
            if (nv > v0) { v1 = v0; i1 = i0; v0 = nv; i0 = e; }
            else if (nv > v1) { v1 = nv; i1 = e; }
        }
        float e1 = expf(v1 - v0);
        float inv = 1.f / (1.f + e1);
        tops[t] = i0 | (i1 << 8);
        gpair[2 * t]     = inv;
        gpair[2 * t + 1] = e1 * inv;
    }
}

// ---------------- build: deterministic per-expert compaction (no atomics) ----------------
__global__ void build_kernel(const int* __restrict__ tops, const float* __restrict__ gpair,
                             int* __restrict__ counts, int* __restrict__ list,
                             float* __restrict__ glist, int* __restrict__ tokslot, int T) {
    int e = blockIdx.x;
    int tid = threadIdx.x, lane = tid & 63, wv = tid >> 6;
    __shared__ int wsum[4];
    __shared__ int sbase;
    if (tid == 0) sbase = 0;
    __syncthreads();
    for (int t0 = 0; t0 < T; t0 += 256) {
        int t = t0 + tid;
        int pk = tops[t];
        int i0 = pk & 0xff, i1 = (pk >> 8) & 0xff;
        bool f0 = (i0 == e), f1 = (i1 == e);
        bool f = f0 || f1;
        unsigned long long m = __ballot(f);
        int lpos = __popcll(m & (((unsigned long long)1 << lane) - 1ull));
        if (lane == 0) wsum[wv] = __popcll(m);
        __syncthreads();
        int woff = sbase;
        for (int w = 0; w < wv; w++) woff += wsum[w];
        int tot = wsum[0] + wsum[1] + wsum[2] + wsum[3];
        if (f) {
            int pos = woff + lpos;
            list[e * T + pos]  = t;
            glist[e * T + pos] = f0 ? gpair[2 * t] : gpair[2 * t + 1];
            tokslot[2 * t + (f0 ? 0 : 1)] = (e << 16) | pos;
        }
        __syncthreads();
        if (tid == 0) sbase += tot;
    }
    __syncthreads();
    if (tid == 0) counts[e] = sbase;
}

// ---------------- scan + compact block map (256-row M-blocks) ----------------
__global__ void scan_kernel(const int* __restrict__ counts, int* __restrict__ offsets,
                            int* __restrict__ bmap, int* __restrict__ nb) {
    if (threadIdx.x == 0 && blockIdx.x == 0) {
        int s = 0, t = 0;
        for (int e = 0; e < NE; e++) {
            offsets[e] = s;
            int c = counts[e];
            s += c;
            int m = (c + 255) >> 8;
            for (int i = 0; i < m; i++) bmap[t++] = (e << 16) | i;
        }
        offsets[NE] = s;
        nb[0] = t;
    }
}

// ===================== 256x256 GEMM, BK=64, 2 static dbufs, 4 quadrant-phases/tile ==========
// 8 waves: wr=wid>>2 (M), wc4=wid&3 (N). Phase (mq,nq) touches ONLY A-half mq, B-half nq:
//   A row(mi)  = (mi>>2)*128 + wr*64 + (mi&3)*16 + r
//   B row(ni)  = (ni>>1)*128 + wc4*32 + (ni&1)*16 + r
// Staging per tile u: P1->A-h1(u+1), P2->B-h1(u+1), P3->A-h0(u+2), P4->B-h0(u+2)
// (target half always freed >=1 phase earlier; first read 4-6 phases after stage)
// Waits: vmcnt(6) end of P1, vmcnt(8) end of P4 (exact per-wave accounting, 8 loads/tile/wave).
// LDS XOR swizzle on 16B chunks: chunk' = chunk ^ (row&7); gl2lds dest linear, source pre-swizzled.

#define PH_RD_A(B, MQ) { \
    _Pragma("unroll") for (int m4 = 0; m4 < 4; m4++) { \
        aF[m4][0] = *(const short8*)&lds[B][0][(MQ)*8192 + aRow + m4*1024 + cA0]; \
        aF[m4][1] = *(const short8*)&lds[B][0][(MQ)*8192 + aRow + m4*1024 + cA1]; } }

#define PH_RD_B(B, NQ) { \
    _Pragma("unroll") for (int n2 = 0; n2 < 2; n2++) { \
        bF[n2][0] = *(const short8*)&lds[B][1][(NQ)*8192 + bRow + n2*1024 + cA0]; \
        bF[n2][1] = *(const short8*)&lds[B][1][(NQ)*8192 + bRow + n2*1024 + cA1]; } }

#define PH_MMA(MQ, NQ) do { \
    __builtin_amdgcn_s_setprio(1); \
    _Pragma("unroll") for (int m4 = 0; m4 < 4; m4++) \
        _Pragma("unroll") for (int n2 = 0; n2 < 2; n2++) { \
            acc[(MQ)*4+m4][(NQ)*2+n2] = mfma16(aF[m4][0], bF[n2][0], acc[(MQ)*4+m4][(NQ)*2+n2]); \
            acc[(MQ)*4+m4][(NQ)*2+n2] = mfma16(aF[m4][1], bF[n2][1], acc[(MQ)*4+m4][(NQ)*2+n2]); } \
    __builtin_amdgcn_s_setprio(0); } while (0)

#define STAGE(B, AB, H, p0, p1) do { \
    u16* d_ = &lds[B][AB][(H)*8192 + wid*512]; \
    gl2lds(p0, d_); gl2lds(p1, d_ + 4096); \
    p0 += 64; p1 += 64; } while (0)

#define G_TILE(B, u, nt) do { \
    /* P1 (mq0,nq0) */ \
    PH_RD_A(B, 0); PH_RD_B(B, 0); \
    if ((u) + 1 < (nt)) STAGE((B)^1, 0, 1, pA10, pA11); \
    SBAR(); WAIT_LGKM0(); \
    PH_MMA(0, 0); \
    WAIT_VM6(); \
    SBAR(); \
    /* P2 (mq0,nq1) */ \
    PH_RD_B(B, 1); \
    if ((u) + 1 < (nt)) STAGE((B)^1, 1, 1, pB10, pB11); \
    SBAR(); WAIT_LGKM0(); \
    PH_MMA(0, 1); \
    SBAR(); \
    /* P3 (mq1,nq0) */ \
    PH_RD_A(B, 1); PH_RD_B(B, 0); \
    if ((u) + 2 < (nt)) STAGE(B, 0, 0, pA00, pA01); \
    SBAR(); WAIT_LGKM0(); \
    PH_MMA(1, 0); \
    SBAR(); \
    /* P4 (mq1,nq1) */ \
    PH_RD_B(B, 1); \
    if ((u) + 2 < (nt)) STAGE(B, 1, 0, pB00, pB01); \
    SBAR(); WAIT_LGKM0(); \
    PH_MMA(1, 1); \
    WAIT_VM8(); \
    SBAR(); } while (0)

// ---------------- GEMM1: xb(gathered) @ wc^T; epilogue silu(h1)*h3*gate -> hb ----------------
__launch_bounds__(512, 2)
__global__ void gemm1_kernel(const u16* __restrict__ xb, const u16* __restrict__ wc,
                             const int* __restrict__ counts, const int* __restrict__ offsets,
                             const int* __restrict__ list, const float* __restrict__ glist,
                             const int* __restrict__ bmap, const int* __restrict__ nb,
                             u16* __restrict__ hb, int T, int D, int H) {
    if ((int)blockIdx.y >= nb[0]) return;
    int info = bmap[blockIdx.y];
    int e = info >> 16, mblk = info & 0xffff, nblk = blockIdx.x;
    int count = counts[e];

    __shared__ u16 lds[2][2][16384];   // [buf][A/B][256 rows x 64 cols]
    __shared__ int stok[256];
    __shared__ float sgate[256];

    int tid = threadIdx.x;
    int lane = tid & 63, wid = tid >> 6;

    if (tid < 256) {
        int rr = min(mblk * 256 + tid, count - 1);
        stok[tid]  = list[e * T + rr];
        sgate[tid] = glist[e * T + rr];
    }
    __syncthreads();

    const u16* wcp = wc + ((size_t)e * 2 * H + (size_t)nblk * 256) * D;

    // staging thread map: row_local = tid>>3 (0..63), c8 = tid&7, pre-swizzled global chunk
    int row_local = tid >> 3, c8 = tid & 7;
    int c_glob = c8 ^ (row_local & 7);
    const u16* pA00 = xb + (size_t)stok[row_local] * D + c_glob * 8;
    const u16* pA01 = xb + (size_t)stok[64 + row_local] * D + c_glob * 8;
    const u16* pA10 = xb + (size_t)stok[128 + row_local] * D + c_glob * 8;
    const u16* pA11 = xb + (size_t)stok[192 + row_local] * D + c_glob * 8;
    const u16* pB00 = wcp + (size_t)row_local * D + c_glob * 8;
    const u16* pB01 = wcp + (size_t)(64 + row_local) * D + c_glob * 8;
    const u16* pB10 = wcp + (size_t)(128 + row_local) * D + c_glob * 8;
    const u16* pB11 = wcp + (size_t)(192 + row_local) * D + c_glob * 8;

    // frag-read lane map
    int r = lane & 15, q = lane >> 4;
    int swz = r & 7;
    int cA0 = (q ^ swz) * 8;
    int cA1 = ((q + 4) ^ swz) * 8;
    int wr = wid >> 2, wc4 = wid & 3;
    int aRow = (wr * 64 + r) * 64;
    int bRow = (wc4 * 32 + r) * 64;

    f32x4 acc[8][4];
#pragma unroll
    for (int mi = 0; mi < 8; mi++)
#pragma unroll
        for (int ni = 0; ni < 4; ni++) acc[mi][ni] = (f32x4)0.f;

    short8 aF[4][2], bF[2][2];

    // prologue: tile0 all 4 halves + tile1 A-h0,B-h0 (6 halves = 12 loads/wave)
    STAGE(0, 0, 0, pA00, pA01);
    STAGE(0, 0, 1, pA10, pA11);
    STAGE(0, 1, 0, pB00, pB01);
    STAGE(0, 1, 1, pB10, pB11);
    STAGE(1, 0, 0, pA00, pA01);
    STAGE(1, 1, 0, pB00, pB01);
    WAIT_VM6();
    SBAR();

    const int nt = D >> 6;      // 16 K-tiles of BK=64
    for (int u = 0; u < nt; u += 2) {
        G_TILE(0, u, nt);
        G_TILE(1, u + 1, nt);
    }

    // epilogue: acc[mi][2a]=h1, acc[mi][2a+1]=h3 at same H-col (16-row interleaved wc)
    int hrow0 = offsets[e];
#pragma unroll
    for (int mi = 0; mi < 8; mi++) {
        int lrow0 = (mi >> 2) * 128 + wr * 64 + (mi & 3) * 16 + q * 4;
#pragma unroll
        for (int a = 0; a < 2; a++) {
            int col = nblk * 128 + a * 64 + wc4 * 16 + r;
#pragma unroll
            for (int tt = 0; tt < 4; tt++) {
                int lrow = lrow0 + tt;
                int grow = mblk * 256 + lrow;
                if (grow < count) {
                    float v = acc[mi][2 * a][tt];
                    float hv = v / (1.f + expf(-v)) * acc[mi][2 * a + 1][tt] * sgate[lrow];
                    hb[(size_t)(hrow0 + grow) * H + col] = f2bf(hv);
                }
            }
        }
    }
}

// ---------------- GEMM2: o2[row] = h[row] @ w2^T ----------------
__launch_bounds__(512, 2)
__global__ void gemm2_kernel(const u16* __restrict__ hb, const u16* __restrict__ w2b,
                             const int* __restrict__ counts, const int* __restrict__ offsets,
                             const int* __restrict__ bmap, const int* __restrict__ nb,
                             float* __restrict__ o2, int T, int D, int H) {
    if ((int)blockIdx.y >= nb[0]) return;
    int info = bmap[blockIdx.y];
    int e = info >> 16, mblk = info & 0xffff, nblk = blockIdx.x;
    int count = counts[e];

    __shared__ u16 lds[2][2][16384];

    int tid = threadIdx.x;
    int lane = tid & 63, wid = tid >> 6;
    int off0 = offsets[e];
    const u16* w2p = w2b + ((size_t)e * D + (size_t)nblk * 256) * H;

    int row_local = tid >> 3, c8 = tid & 7;
    int c_glob = c8 ^ (row_local & 7);
    int ra00 = min(mblk * 256 + row_local, count - 1);
    int ra01 = min(mblk * 256 + 64 + row_local, count - 1);
    int ra10 = min(mblk * 256 + 128 + row_local, count - 1);
    int ra11 = min(mblk * 256 + 192 + row_local, count - 1);
    const u16* pA00 = hb + (size_t)(off0 + ra00) * H + c_glob * 8;
    const u16* pA01 = hb + (size_t)(off0 + ra01) * H + c_glob * 8;
    const u16* pA10 = hb + (size_t)(off0 + ra10) * H + c_glob * 8;
    const u16* pA11 = hb + (size_t)(off0 + ra11) * H + c_glob * 8;
    const u16* pB00 = w2p + (size_t)row_local * H + c_glob * 8;
    const u16* pB01 = w2p + (size_t)(64 + row_local) * H + c_glob * 8;
    const u16* pB10 = w2p + (size_t)(128 + row_local) * H + c_glob * 8;
    const u16* pB11 = w2p + (size_t)(192 + row_local) * H + c_glob * 8;

    int r = lane & 15, q = lane >> 4;
    int swz = r & 7;
    int cA0 = (q ^ swz) * 8;
    int cA1 = ((q + 4) ^ swz) * 8;
    int wr = wid >> 2, wc4 = wid & 3;
    int aRow = (wr * 64 + r) * 64;
    int bRow = (wc4 * 32 + r) * 64;

    f32x4 acc[8][4];
#pragma unroll
    for (int mi = 0; mi < 8; mi++)
#pragma unroll
        for (int ni = 0; ni < 4; ni++) acc[mi][ni] = (f32x4)0.f;

    short8 aF[4][2], bF[2][2];

    STAGE(0, 0, 0, pA00, pA01);
    STAGE(0, 0, 1, pA10, pA11);
    STAGE(0, 1, 0, pB00, pB01);
    STAGE(0, 1, 1, pB10, pB11);
    STAGE(1, 0, 0, pA00, pA01);
    STAGE(1, 1, 0, pB00, pB01);
    WAIT_VM6();
    SBAR();

    const int nt = H >> 6;      // 32 K-tiles
    for (int u = 0; u < nt; u += 2) {
        G_TILE(0, u, nt);
        G_TILE(1, u + 1, nt);
    }

    // epilogue: packed fp32 stores
#pragma unroll
    for (int mi = 0; mi < 8; mi++) {
        int lrow0 = (mi >> 2) * 128 + wr * 64 + (mi & 3) * 16 + q * 4;
#pragma unroll
        for (int tt = 0; tt < 4; tt++) {
            int grow = mblk * 256 + lrow0 + tt;
            if (grow < count) {
#pragma unroll
                for (int ni = 0; ni < 4; ni++) {
                    int col = nblk * 256 + (ni >> 1) * 128 + wc4 * 32 + (ni & 1) * 16 + r;
                    o2[(size_t)(off0 + grow) * D + col] = acc[mi][ni][tt];
                }
            }
        }
    }
}

// ---------------- combine: out[t] = o2[row0(t)] + o2[row1(t)] ----------------
__global__ void combine_kernel(const float* __restrict__ o2, const int* __restrict__ tokslot,
                               const int* __restrict__ offsets, float* __restrict__ out, int D) {
    int t = blockIdx.x;
    int s0 = tokslot[2 * t], s1 = tokslot[2 * t + 1];
    size_t r0 = offsets[s0 >> 16] + (s0 & 0xffff);
    size_t r1 = offsets[s1 >> 16] + (s1 & 0xffff);
    int c = threadIdx.x * 4;
    float4 a = *(const float4*)(o2 + r0 * D + c);
    float4 b = *(const float4*)(o2 + r1 * D + c);
    float4 o; o.x = a.x + b.x; o.y = a.y + b.y; o.z = a.z + b.z; o.w = a.w + b.w;
    *(float4*)(out + (size_t)t * D + c) = o;
}

extern "C" void kernel_launch(void* const* d_in, const int* in_sizes, int n_in,
                              void* d_out, int out_size, void* d_ws, size_t ws_size,
                              hipStream_t stream) {
    const float* x     = (const float*)d_in[0];
    const float* noise = (const float*)d_in[1];
    const float* rw    = (const float*)d_in[2];
    const float* rb    = (const float*)d_in[3];
    const float* nw    = (const float*)d_in[4];
    const float* nb_   = (const float*)d_in[5];
    const float* w1    = (const float*)d_in[6];
    const float* w2    = (const float*)d_in[7];
    const float* w3    = (const float*)d_in[8];
    float* out = (float*)d_out;

    const int E = NE;
    const int D = in_sizes[2] / E;              // 1024
    const int T = in_sizes[0] / D;              // 8192
    const int H = in_sizes[6] / (E * D);        // 2048

    auto al = [](size_t v) { return (v + 255) & ~(size_t)255; };
    char* p = (char*)d_ws;
    size_t o_counts  = 0;                                     // 8 ints
    size_t o_offsets = 64;                                    // 9 ints
    size_t o_nb      = 128;                                   // 1 int
    size_t o_bmap    = 256;                                   // up to 2T/256+NE ints
    size_t o_tslot   = al(o_bmap  + 2048);
    size_t o_list    = al(o_tslot + (size_t)2 * T * 4);
    size_t o_glist   = al(o_list  + (size_t)E * T * 4);
    size_t o_xb      = al(o_glist + (size_t)E * T * 4);
    size_t o_wc      = al(o_xb    + (size_t)T * D * 2);       // wc reused as o2 after gemm1
    size_t o_w2b     = al(o_wc    + (size_t)E * 2 * H * D * 2);
    size_t o_hb      = al(o_w2b   + (size_t)E * D * H * 2);

    int*   counts  = (int*)(p + o_counts);
    int*   offsets = (int*)(p + o_offsets);
    int*   nblk    = (int*)(p + o_nb);
    int*   bmap    = (int*)(p + o_bmap);
    int*   tokslot = (int*)(p + o_tslot);
    int*   list    = (int*)(p + o_list);
    float* glist   = (float*)(p + o_glist);
    u16*   xb      = (u16*)(p + o_xb);
    u16*   wc      = (u16*)(p + o_wc);
    float* o2      = (float*)(p + o_wc);        // overlay: wc dead after gemm1
    u16*   w2b     = (u16*)(p + o_w2b);
    u16*   hb      = (u16*)(p + o_hb);
    // tops/gpair overlay head of hb region: dead before gemm1 writes hb.
    int*   tops    = (int*)(p + o_hb);                        // T ints   (32 KB)
    float* gpair   = (float*)(p + o_hb + (size_t)T * 4);      // 2T floats (64 KB)

    cvt_w13_kernel<<<2048, 256, 0, stream>>>(w1, w3, wc, H, D);
    cvt_kernel<<<2048, 256, 0, stream>>>(w2, w2b, (size_t)E * D * H / 4);

    router_kernel<<<(T + 3) / 4, 256, 0, stream>>>(x, noise, rw, rb, nw, nb_,
                                                   tops, gpair, xb, T, D);
    build_kernel<<<NE, 256, 0, stream>>>(tops, gpair, counts, list, glist, tokslot, T);
    scan_kernel<<<1, 64, 0, stream>>>(counts, offsets, bmap, nblk);

    int maxb = 2 * T / 256 + NE;                // 72
    dim3 g1(2 * H / 256, maxb, 1);              // (16, 72)
    gemm1_kernel<<<g1, 512, 0, stream>>>(xb, wc, counts, offsets, list, glist,
                                         bmap, nblk, hb, T, D, H);
    dim3 g2(D / 256, maxb, 1);                  // (4, 72)
    gemm2_kernel<<<g2, 512, 0, stream>>>(hb, w2b, counts, offsets,
                                         bmap, nblk, o2, T, D, H);
    combine_kernel<<<T, 256, 0, stream>>>(o2, tokslot, offsets, out, D);
}

// Round 4
// 623.576 us; speedup vs baseline: 1.0577x; 1.0024x over previous
//
#include <hip/hip_runtime.h>

typedef unsigned short u16;
typedef __attribute__((ext_vector_type(8))) __bf16 bf16x8;
typedef __attribute__((ext_vector_type(8))) short short8;
typedef __attribute__((ext_vector_type(4))) float f32x4;

#define NE 8            // experts

#define SBAR()   asm volatile("s_barrier" ::: "memory")
#define WVM0()   asm volatile("s_waitcnt vmcnt(0)" ::: "memory")
#define WVM8()   asm volatile("s_waitcnt vmcnt(8)" ::: "memory")
#define WVM10()  asm volatile("s_waitcnt vmcnt(10)" ::: "memory")

__device__ __forceinline__ u16 f2bf(float f) {
    union { float f; unsigned u; } v; v.f = f;
    unsigned u = v.u;
    return (u16)((u + 0x7fffu + ((u >> 16) & 1u)) >> 16);
}

__device__ __forceinline__ f32x4 mfma16(short8 a, short8 b, f32x4 c) {
    return __builtin_amdgcn_mfma_f32_16x16x32_bf16(
        __builtin_bit_cast(bf16x8, a), __builtin_bit_cast(bf16x8, b), c, 0, 0, 0);
}

// async global->LDS, 16B per lane; lds dest = wave-uniform base + lane*16
__device__ __forceinline__ void gl2lds(const u16* g, u16* l) {
    __builtin_amdgcn_global_load_lds((const __attribute__((address_space(1))) void*)g,
                                     (__attribute__((address_space(3))) void*)l,
                                     16, 0, 0);
}

// ---------------- w2 fp32 -> bf16 (grid-stride, float4) ----------------
__global__ void cvt_kernel(const float* __restrict__ in, u16* __restrict__ out, size_t n4) {
    size_t i = (size_t)blockIdx.x * blockDim.x + threadIdx.x;
    size_t stride = (size_t)gridDim.x * blockDim.x;
    for (; i < n4; i += stride) {
        float4 v = ((const float4*)in)[i];
        ushort4 o;
        o.x = f2bf(v.x); o.y = f2bf(v.y); o.z = f2bf(v.z); o.w = f2bf(v.w);
        ((ushort4*)out)[i] = o;
    }
}

// ---- w1/w3 -> bf16 wc[e][2H][D], 16-row interleave:
//      H-col j -> w1 at wc row (j>>4)*32 + (j&15); w3 at +16.
__global__ void cvt_w13_kernel(const float* __restrict__ w1, const float* __restrict__ w3,
                               u16* __restrict__ wc, int H, int D) {
    size_t n = (size_t)NE * H * (D / 4);
    size_t i = (size_t)blockIdx.x * blockDim.x + threadIdx.x;
    size_t stride = (size_t)gridDim.x * blockDim.x;
    int d4n = D / 4;
    for (; i < n; i += stride) {
        int d4 = (int)(i % d4n);
        size_t rem = i / d4n;
        int j = (int)(rem % H);
        int e = (int)(rem / H);
        float4 v1 = ((const float4*)w1)[i];
        float4 v3 = ((const float4*)w3)[i];
        ushort4 o1, o3;
        o1.x = f2bf(v1.x); o1.y = f2bf(v1.y); o1.z = f2bf(v1.z); o1.w = f2bf(v1.w);
        o3.x = f2bf(v3.x); o3.y = f2bf(v3.y); o3.z = f2bf(v3.z); o3.w = f2bf(v3.w);
        int wcrow = ((j >> 4) << 5) + (j & 15);
        size_t o = (((size_t)e * 2 * H + wcrow) * d4n + d4);
        ((ushort4*)wc)[o] = o1;
        ((ushort4*)wc)[o + (size_t)16 * d4n] = o3;
    }
}

// ---------------- router: noisy top-2 gating + x->bf16, one wave per token ----------------
__global__ void router_kernel(const float* __restrict__ x, const float* __restrict__ noise,
                              const float* __restrict__ rw, const float* __restrict__ rb,
                              const float* __restrict__ nw, const float* __restrict__ nb,
                              int* __restrict__ tops, float* __restrict__ gpair,
                              u16* __restrict__ xb, int T, int D) {
    int wv = threadIdx.x >> 6;
    int lane = threadIdx.x & 63;
    int t = blockIdx.x * 4 + wv;
    if (t >= T) return;

    const float4* x4 = (const float4*)(x + (size_t)t * D) + lane * 4;
    float4 xv0 = x4[0], xv1 = x4[1], xv2 = x4[2], xv3 = x4[3];

    {
        ushort4 s0, s1, s2, s3;
        s0.x = f2bf(xv0.x); s0.y = f2bf(xv0.y); s0.z = f2bf(xv0.z); s0.w = f2bf(xv0.w);
        s1.x = f2bf(xv1.x); s1.y = f2bf(xv1.y); s1.z = f2bf(xv1.z); s1.w = f2bf(xv1.w);
        s2.x = f2bf(xv2.x); s2.y = f2bf(xv2.y); s2.z = f2bf(xv2.z); s2.w = f2bf(xv2.w);
        s3.x = f2bf(xv3.x); s3.y = f2bf(xv3.y); s3.z = f2bf(xv3.z); s3.w = f2bf(xv3.w);
        ushort4* o = (ushort4*)(xb + (size_t)t * D + lane * 16);
        o[0] = s0; o[1] = s1; o[2] = s2; o[3] = s3;
    }

    float acc[2 * NE];
#pragma unroll
    for (int e = 0; e < NE; e++) {
        const float4* w4 = (const float4*)(rw + (size_t)e * D) + lane * 4;
        float4 a = w4[0], b = w4[1], c = w4[2], d = w4[3];
        acc[e] = xv0.x*a.x + xv0.y*a.y + xv0.z*a.z + xv0.w*a.w
               + xv1.x*b.x + xv1.y*b.y + xv1.z*b.z + xv1.w*b.w
               + xv2.x*c.x + xv2.y*c.y + xv2.z*c.z + xv2.w*c.w
               + xv3.x*d.x + xv3.y*d.y + xv3.z*d.z + xv3.w*d.w;
        const float4* v4 = (const float4*)(nw + (size_t)e * D) + lane * 4;
        a = v4[0]; b = v4[1]; c = v4[2]; d = v4[3];
        acc[NE + e] = xv0.x*a.x + xv0.y*a.y + xv0.z*a.z + xv0.w*a.w
                    + xv1.x*b.x + xv1.y*b.y + xv1.z*b.z + xv1.w*b.w
                    + xv2.x*c.x + xv2.y*c.y + xv2.z*c.z + xv2.w*c.w
                    + xv3.x*d.x + xv3.y*d.y + xv3.z*d.z + xv3.w*d.w;
    }
#pragma unroll
    for (int m = 1; m < 64; m <<= 1) {
#pragma unroll
        for (int k = 0; k < 2 * NE; k++) acc[k] += __shfl_xor(acc[k], m);
    }

    if (lane == 0) {
        float v0 = -1e30f, v1 = -1e30f;
        int i0 = 0, i1 = 0;
#pragma unroll
        for (int e = 0; e < NE; e++) {
            float z = acc[NE + e] + nb[e];
            float sp = (z > 20.f) ? z : log1pf(expf(z));
            float nv = acc[e] + rb[e] + noise[(size_t)t * NE + e] * sp;
            if (nv > v0) { v1 = v0; i1 = i0; v0 = nv; i0 = e; }
            else if (nv > v1) { v1 = nv; i1 = e; }
        }
        float e1 = expf(v1 - v0);
        float inv = 1.f / (1.f + e1);
        tops[t] = i0 | (i1 << 8);
        gpair[2 * t]     = inv;
        gpair[2 * t + 1] = e1 * inv;
    }
}

// ---------------- build: deterministic per-expert compaction (no atomics) ----------------
__global__ void build_kernel(const int* __restrict__ tops, const float* __restrict__ gpair,
                             int* __restrict__ counts, int* __restrict__ list,
                             float* __restrict__ glist, int* __restrict__ tokslot, int T) {
    int e = blockIdx.x;
    int tid = threadIdx.x, lane = tid & 63, wv = tid >> 6;
    __shared__ int wsum[4];
    __shared__ int sbase;
    if (tid == 0) sbase = 0;
    __syncthreads();
    for (int t0 = 0; t0 < T; t0 += 256) {
        int t = t0 + tid;
        int pk = tops[t];
        int i0 = pk & 0xff, i1 = (pk >> 8) & 0xff;
        bool f0 = (i0 == e), f1 = (i1 == e);
        bool f = f0 || f1;
        unsigned long long m = __ballot(f);
        int lpos = __popcll(m & (((unsigned long long)1 << lane) - 1ull));
        if (lane == 0) wsum[wv] = __popcll(m);
        __syncthreads();
        int woff = sbase;
        for (int w = 0; w < wv; w++) woff += wsum[w];
        int tot = wsum[0] + wsum[1] + wsum[2] + wsum[3];
        if (f) {
            int pos = woff + lpos;
            list[e * T + pos]  = t;
            glist[e * T + pos] = f0 ? gpair[2 * t] : gpair[2 * t + 1];
            tokslot[2 * t + (f0 ? 0 : 1)] = (e << 16) | pos;
        }
        __syncthreads();
        if (tid == 0) sbase += tot;
    }
    __syncthreads();
    if (tid == 0) counts[e] = sbase;
}

// ---------------- scan + compact block map (256-row M-blocks) ----------------
__global__ void scan_kernel(const int* __restrict__ counts, int* __restrict__ offsets,
                            int* __restrict__ bmap, int* __restrict__ nb) {
    if (threadIdx.x == 0 && blockIdx.x == 0) {
        int s = 0, t = 0;
        for (int e = 0; e < NE; e++) {
            offsets[e] = s;
            int c = counts[e];
            s += c;
            int m = (c + 255) >> 8;
            for (int i = 0; i < m; i++) bmap[t++] = (e << 16) | i;
        }
        offsets[NE] = s;
        nb[0] = t;
    }
}

// ===================== 256x256 GEMM, BK=64, 2 static dbufs, snake-pipelined phases ==========
// 8 waves (2M x 4N), per-wave C 128x64. Quadrant order (0,0)->(0,1)->(1,1)->(1,0):
//   P1: read aX<-A-h0, bX<-B-h0, bY<-B-h1 (bY hides under P1 MFMA); MMA aX*bX
//   P2: MMA aX*bY           P3: refill aX<-A-h1; MMA aX*bY      P4: MMA aX*bX
// Staging slots (per tile t): P1->A-h1(t+1); P2->A-h0(t+2); P3->B-h0(t+2)+B-h1(t+2).
// Waits at phase END (before SBAR, cross-wave visibility): P2-end vmcnt(10), P4-end vmcnt(8)
// (exact per-wave in-flight accounting; vmcnt(0) only for last 2 tiles).
// No lgkm asm / sched_barrier: C++ ds_reads let the compiler emit fine-grained lgkmcnt(N).
// LDS XOR swizzle (16B chunks): slot c holds global chunk c^(row&7); verified 0 conflicts.

#define RD_A(BUF, MQ) { \
    _Pragma("unroll") for (int m4 = 0; m4 < 4; m4++) { \
        aX[m4][0] = *(const short8*)&lds[BUF][0][(MQ)*8192 + aRow + m4*1024 + cA0]; \
        aX[m4][1] = *(const short8*)&lds[BUF][0][(MQ)*8192 + aRow + m4*1024 + cA1]; } }

#define RD_B(BUF, NQ, BR) { \
    _Pragma("unroll") for (int n2 = 0; n2 < 2; n2++) { \
        BR[n2][0] = *(const short8*)&lds[BUF][1][(NQ)*8192 + bRow + n2*1024 + cA0]; \
        BR[n2][1] = *(const short8*)&lds[BUF][1][(NQ)*8192 + bRow + n2*1024 + cA1]; } }

#define MMA(MQ, NQ, BR) do { \
    __builtin_amdgcn_s_setprio(1); \
    _Pragma("unroll") for (int m4 = 0; m4 < 4; m4++) \
        _Pragma("unroll") for (int n2 = 0; n2 < 2; n2++) { \
            acc[(MQ)*4+m4][(NQ)*2+n2] = mfma16(aX[m4][0], BR[n2][0], acc[(MQ)*4+m4][(NQ)*2+n2]); \
            acc[(MQ)*4+m4][(NQ)*2+n2] = mfma16(aX[m4][1], BR[n2][1], acc[(MQ)*4+m4][(NQ)*2+n2]); } \
    __builtin_amdgcn_s_setprio(0); } while (0)

#define STAGE(BUF, AB, HF, p0, p1) do { \
    u16* d_ = &lds[BUF][AB][(HF)*8192 + wid*512]; \
    gl2lds(p0, d_); gl2lds(p1, d_ + 4096); \
    p0 += 64; p1 += 64; } while (0)

#define TILE(BUF, t, nt) do { \
    bool tail = (t) >= (nt) - 2; \
    /* P1 */ \
    if ((t) + 1 < (nt)) STAGE(BUF ^ 1, 0, 1, pA10, pA11); \
    RD_A(BUF, 0); RD_B(BUF, 0, bX); RD_B(BUF, 1, bY); \
    MMA(0, 0, bX); \
    SBAR(); \
    /* P2 */ \
    if ((t) + 2 < (nt)) STAGE(BUF, 0, 0, pA00, pA01); \
    MMA(0, 1, bY); \
    if (tail) { WVM0(); } else { WVM10(); } \
    SBAR(); \
    /* P3 */ \
    if ((t) + 2 < (nt)) { STAGE(BUF, 1, 0, pB00, pB01); STAGE(BUF, 1, 1, pB10, pB11); } \
    RD_A(BUF, 1); \
    MMA(1, 1, bY); \
    SBAR(); \
    /* P4 */ \
    MMA(1, 0, bX); \
    if (tail) { WVM0(); } else { WVM8(); } \
    SBAR(); } while (0)

// prologue slot order (virtual tiles -2,-1): A0(0),B0(0),B1(0),A1(0),A0(1),B0(1),B1(1)
#define GEMM_PROLOGUE() do { \
    STAGE(0, 0, 0, pA00, pA01); \
    STAGE(0, 1, 0, pB00, pB01); \
    STAGE(0, 1, 1, pB10, pB11); \
    STAGE(0, 0, 1, pA10, pA11); \
    STAGE(1, 0, 0, pA00, pA01); \
    STAGE(1, 1, 0, pB00, pB01); \
    STAGE(1, 1, 1, pB10, pB11); \
    WVM8(); \
    SBAR(); } while (0)

// ---------------- GEMM1: xb(gathered) @ wc^T; epilogue silu(h1)*h3*gate -> hb ----------------
__launch_bounds__(512, 2)
__global__ void gemm1_kernel(const u16* __restrict__ xb, const u16* __restrict__ wc,
                             const int* __restrict__ counts, const int* __restrict__ offsets,
                             const int* __restrict__ list, const float* __restrict__ glist,
                             const int* __restrict__ bmap, const int* __restrict__ nb,
                             u16* __restrict__ hb, int T, int D, int H) {
    if ((int)blockIdx.y >= nb[0]) return;
    int info = bmap[blockIdx.y];
    int e = info >> 16, mblk = info & 0xffff, nblk = blockIdx.x;
    int count = counts[e];

    __shared__ u16 lds[2][2][16384];   // [buf][A/B][256 rows x 64 cols]
    __shared__ int stok[256];
    __shared__ float sgate[256];

    int tid = threadIdx.x;
    int lane = tid & 63, wid = tid >> 6;

    if (tid < 256) {
        int rr = min(mblk * 256 + tid, count - 1);
        stok[tid]  = list[e * T + rr];
        sgate[tid] = glist[e * T + rr];
    }
    __syncthreads();

    const u16* wcp = wc + ((size_t)e * 2 * H + (size_t)nblk * 256) * D;

    // staging thread map: row_local = tid>>3 (0..63), c8 = tid&7, pre-swizzled global chunk
    int row_local = tid >> 3, c8 = tid & 7;
    int c_glob = c8 ^ (row_local & 7);
    const u16* pA00 = xb + (size_t)stok[row_local] * D + c_glob * 8;
    const u16* pA01 = xb + (size_t)stok[64 + row_local] * D + c_glob * 8;
    const u16* pA10 = xb + (size_t)stok[128 + row_local] * D + c_glob * 8;
    const u16* pA11 = xb + (size_t)stok[192 + row_local] * D + c_glob * 8;
    const u16* pB00 = wcp + (size_t)row_local * D + c_glob * 8;
    const u16* pB01 = wcp + (size_t)(64 + row_local) * D + c_glob * 8;
    const u16* pB10 = wcp + (size_t)(128 + row_local) * D + c_glob * 8;
    const u16* pB11 = wcp + (size_t)(192 + row_local) * D + c_glob * 8;

    // frag-read lane map
    int r = lane & 15, q = lane >> 4;
    int swz = r & 7;
    int cA0 = (q ^ swz) * 8;
    int cA1 = ((q + 4) ^ swz) * 8;
    int wr = wid >> 2, wc4 = wid & 3;
    int aRow = (wr * 64 + r) * 64;
    int bRow = (wc4 * 32 + r) * 64;

    f32x4 acc[8][4];
#pragma unroll
    for (int mi = 0; mi < 8; mi++)
#pragma unroll
        for (int ni = 0; ni < 4; ni++) acc[mi][ni] = (f32x4)0.f;

    short8 aX[4][2], bX[2][2], bY[2][2];

    GEMM_PROLOGUE();

    const int nt = D >> 6;      // 16 K-tiles of BK=64
#pragma unroll 1
    for (int t = 0; t < nt; t += 2) {
        TILE(0, t, nt);
        TILE(1, t + 1, nt);
    }

    // epilogue: acc[mi][2a]=h1, acc[mi][2a+1]=h3 at same H-col (16-row interleaved wc)
    int hrow0 = offsets[e];
#pragma unroll
    for (int mi = 0; mi < 8; mi++) {
        int lrow0 = (mi >> 2) * 128 + wr * 64 + (mi & 3) * 16 + q * 4;
#pragma unroll
        for (int a = 0; a < 2; a++) {
            int col = nblk * 128 + a * 64 + wc4 * 16 + r;
#pragma unroll
            for (int tt = 0; tt < 4; tt++) {
                int lrow = lrow0 + tt;
                int grow = mblk * 256 + lrow;
                if (grow < count) {
                    float v = acc[mi][2 * a][tt];
                    float hv = v / (1.f + expf(-v)) * acc[mi][2 * a + 1][tt] * sgate[lrow];
                    hb[(size_t)(hrow0 + grow) * H + col] = f2bf(hv);
                }
            }
        }
    }
}

// ---------------- GEMM2: o2[row] = h[row] @ w2^T ----------------
__launch_bounds__(512, 2)
__global__ void gemm2_kernel(const u16* __restrict__ hb, const u16* __restrict__ w2b,
                             const int* __restrict__ counts, const int* __restrict__ offsets,
                             const int* __restrict__ bmap, const int* __restrict__ nb,
                             float* __restrict__ o2, int T, int D, int H) {
    if ((int)blockIdx.y >= nb[0]) return;
    int info = bmap[blockIdx.y];
    int e = info >> 16, mblk = info & 0xffff, nblk = blockIdx.x;
    int count = counts[e];

    __shared__ u16 lds[2][2][16384];

    int tid = threadIdx.x;
    int lane = tid & 63, wid = tid >> 6;
    int off0 = offsets[e];
    const u16* w2p = w2b + ((size_t)e * D + (size_t)nblk * 256) * H;

    int row_local = tid >> 3, c8 = tid & 7;
    int c_glob = c8 ^ (row_local & 7);
    int ra00 = min(mblk * 256 + row_local, count - 1);
    int ra01 = min(mblk * 256 + 64 + row_local, count - 1);
    int ra10 = min(mblk * 256 + 128 + row_local, count - 1);
    int ra11 = min(mblk * 256 + 192 + row_local, count - 1);
    const u16* pA00 = hb + (size_t)(off0 + ra00) * H + c_glob * 8;
    const u16* pA01 = hb + (size_t)(off0 + ra01) * H + c_glob * 8;
    const u16* pA10 = hb + (size_t)(off0 + ra10) * H + c_glob * 8;
    const u16* pA11 = hb + (size_t)(off0 + ra11) * H + c_glob * 8;
    const u16* pB00 = w2p + (size_t)row_local * H + c_glob * 8;
    const u16* pB01 = w2p + (size_t)(64 + row_local) * H + c_glob * 8;
    const u16* pB10 = w2p + (size_t)(128 + row_local) * H + c_glob * 8;
    const u16* pB11 = w2p + (size_t)(192 + row_local) * H + c_glob * 8;

    int r = lane & 15, q = lane >> 4;
    int swz = r & 7;
    int cA0 = (q ^ swz) * 8;
    int cA1 = ((q + 4) ^ swz) * 8;
    int wr = wid >> 2, wc4 = wid & 3;
    int aRow = (wr * 64 + r) * 64;
    int bRow = (wc4 * 32 + r) * 64;

    f32x4 acc[8][4];
#pragma unroll
    for (int mi = 0; mi < 8; mi++)
#pragma unroll
        for (int ni = 0; ni < 4; ni++) acc[mi][ni] = (f32x4)0.f;

    short8 aX[4][2], bX[2][2], bY[2][2];

    GEMM_PROLOGUE();

    const int nt = H >> 6;      // 32 K-tiles
#pragma unroll 1
    for (int t = 0; t < nt; t += 2) {
        TILE(0, t, nt);
        TILE(1, t + 1, nt);
    }

    // epilogue: packed fp32 stores
#pragma unroll
    for (int mi = 0; mi < 8; mi++) {
        int lrow0 = (mi >> 2) * 128 + wr * 64 + (mi & 3) * 16 + q * 4;
#pragma unroll
        for (int tt = 0; tt < 4; tt++) {
            int grow = mblk * 256 + lrow0 + tt;
            if (grow < count) {
#pragma unroll
                for (int ni = 0; ni < 4; ni++) {
                    int col = nblk * 256 + (ni >> 1) * 128 + wc4 * 32 + (ni & 1) * 16 + r;
                    o2[(size_t)(off0 + grow) * D + col] = acc[mi][ni][tt];
                }
            }
        }
    }
}

// ---------------- combine: out[t] = o2[row0(t)] + o2[row1(t)] ----------------
__global__ void combine_kernel(const float* __restrict__ o2, const int* __restrict__ tokslot,
                               const int* __restrict__ offsets, float* __restrict__ out, int D) {
    int t = blockIdx.x;
    int s0 = tokslot[2 * t], s1 = tokslot[2 * t + 1];
    size_t r0 = offsets[s0 >> 16] + (s0 & 0xffff);
    size_t r1 = offsets[s1 >> 16] + (s1 & 0xffff);
    int c = threadIdx.x * 4;
    float4 a = *(const float4*)(o2 + r0 * D + c);
    float4 b = *(const float4*)(o2 + r1 * D + c);
    float4 o; o.x = a.x + b.x; o.y = a.y + b.y; o.z = a.z + b.z; o.w = a.w + b.w;
    *(float4*)(out + (size_t)t * D + c) = o;
}

extern "C" void kernel_launch(void* const* d_in, const int* in_sizes, int n_in,
                              void* d_out, int out_size, void* d_ws, size_t ws_size,
                              hipStream_t stream) {
    const float* x     = (const float*)d_in[0];
    const float* noise = (const float*)d_in[1];
    const float* rw    = (const float*)d_in[2];
    const float* rb    = (const float*)d_in[3];
    const float* nw    = (const float*)d_in[4];
    const float* nb_   = (const float*)d_in[5];
    const float* w1    = (const float*)d_in[6];
    const float* w2    = (const float*)d_in[7];
    const float* w3    = (const float*)d_in[8];
    float* out = (float*)d_out;

    const int E = NE;
    const int D = in_sizes[2] / E;              // 1024
    const int T = in_sizes[0] / D;              // 8192
    const int H = in_sizes[6] / (E * D);        // 2048

    auto al = [](size_t v) { return (v + 255) & ~(size_t)255; };
    char* p = (char*)d_ws;
    size_t o_counts  = 0;                                     // 8 ints
    size_t o_offsets = 64;                                    // 9 ints
    size_t o_nb      = 128;                                   // 1 int
    size_t o_bmap    = 256;                                   // up to 2T/256+NE ints
    size_t o_tslot   = al(o_bmap  + 2048);
    size_t o_list    = al(o_tslot + (size_t)2 * T * 4);
    size_t o_glist   = al(o_list  + (size_t)E * T * 4);
    size_t o_xb      = al(o_glist + (size_t)E * T * 4);
    size_t o_wc      = al(o_xb    + (size_t)T * D * 2);       // wc reused as o2 after gemm1
    size_t o_w2b     = al(o_wc    + (size_t)E * 2 * H * D * 2);
    size_t o_hb      = al(o_w2b   + (size_t)E * D * H * 2);

    int*   counts  = (int*)(p + o_counts);
    int*   offsets = (int*)(p + o_offsets);
    int*   nblk    = (int*)(p + o_nb);
    int*   bmap    = (int*)(p + o_bmap);
    int*   tokslot = (int*)(p + o_tslot);
    int*   list    = (int*)(p + o_list);
    float* glist   = (float*)(p + o_glist);
    u16*   xb      = (u16*)(p + o_xb);
    u16*   wc      = (u16*)(p + o_wc);
    float* o2      = (float*)(p + o_wc);        // overlay: wc dead after gemm1
    u16*   w2b     = (u16*)(p + o_w2b);
    u16*   hb      = (u16*)(p + o_hb);
    // tops/gpair overlay head of hb region: dead before gemm1 writes hb.
    int*   tops    = (int*)(p + o_hb);                        // T ints   (32 KB)
    float* gpair   = (float*)(p + o_hb + (size_t)T * 4);      // 2T floats (64 KB)

    cvt_w13_kernel<<<2048, 256, 0, stream>>>(w1, w3, wc, H, D);
    cvt_kernel<<<2048, 256, 0, stream>>>(w2, w2b, (size_t)E * D * H / 4);

    router_kernel<<<(T + 3) / 4, 256, 0, stream>>>(x, noise, rw, rb, nw, nb_,
                                                   tops, gpair, xb, T, D);
    build_kernel<<<NE, 256, 0, stream>>>(tops, gpair, counts, list, glist, tokslot, T);
    scan_kernel<<<1, 64, 0, stream>>>(counts, offsets, bmap, nblk);

    int maxb = 2 * T / 256 + NE;                // 72
    dim3 g1(2 * H / 256, maxb, 1);              // (16, 72)
    gemm1_kernel<<<g1, 512, 0, stream>>>(xb, wc, counts, offsets, list, glist,
                                         bmap, nblk, hb, T, D, H);
    dim3 g2(D / 256, maxb, 1);                  // (4, 72)
    gemm2_kernel<<<g2, 512, 0, stream>>>(hb, w2b, counts, offsets,
                                         bmap, nblk, o2, T, D, H);
    combine_kernel<<<T, 256, 0, stream>>>(o2, tokslot, offsets, out, D);
}